// Round 12
// baseline (764.852 us; speedup 1.0000x reference)
//
#include <hip/hip_runtime.h>
#include <hip/hip_bf16.h>

// ROUND 12: OUTPUT IS FLOAT32. Root cause of r2-r11: harness reads d_out as
// fp32 (reference returns float32; "(bf16, ref=np)" in the test label is the
// tolerance mode, not the buffer dtype). My bf16 writes were read as packed
// fp32 pairs -> position-scrambled, correct-scale output -> decorrelation-
// scale absmax (1.15-1.42) for ALL rounds regardless of function correctness.
// Quantitative fit: predicted 1.25-1.35, observed 1.15-1.42; stub = 0.9375 =
// max|ref| exactly; r2==r3==r4 bit-identical => pipeline values were correct
// since round 2. This round: r2's verified pipeline + float* output.
//
// Pipeline (fp32 end-to-end):
//   per layer: 4x LDS-tiled GEMM (q,k,v,skip) -> wave-per-edge pass
//   (shuffle-reduced qk dot, exp, atomic agg/den) -> finalize (agg/den +
//   skip [+relu]); layer-2 finalize stores float to d_out.

#define N_NODES 50000
#define N_EDGES 800000

// ---------------- GEMM: C[N x 64] = A[N x K] * W[64 x K]^T + b ----------------
__global__ __launch_bounds__(256) void gemm_proj(const float* __restrict__ A, int K,
                                                 const float* __restrict__ W,
                                                 const float* __restrict__ b,
                                                 float* __restrict__ C) {
    __shared__ float As[64][33];
    __shared__ float Ws[64][33];
    const int row0 = blockIdx.x * 64;
    const int tid = threadIdx.x;
    const int tr = tid >> 4;      // 0..15 (row group)
    const int tc = tid & 15;      // 0..15 (col group)
    float acc[4][4] = {};

    for (int k0 = 0; k0 < K; k0 += 32) {
        for (int i = tid; i < 64 * 32; i += 256) {
            int r = i >> 5, kk = i & 31;
            int gr = row0 + r;
            As[r][kk] = (gr < N_NODES) ? A[(size_t)gr * K + k0 + kk] : 0.f;
            Ws[r][kk] = W[(size_t)r * K + k0 + kk];
        }
        __syncthreads();
#pragma unroll 8
        for (int kk = 0; kk < 32; ++kk) {
            float a[4], w[4];
#pragma unroll
            for (int i = 0; i < 4; ++i) a[i] = As[tr * 4 + i][kk];
#pragma unroll
            for (int j = 0; j < 4; ++j) w[j] = Ws[tc * 4 + j][kk];
#pragma unroll
            for (int i = 0; i < 4; ++i)
#pragma unroll
                for (int j = 0; j < 4; ++j) acc[i][j] += a[i] * w[j];
        }
        __syncthreads();
    }
#pragma unroll
    for (int i = 0; i < 4; ++i) {
        int r = row0 + tr * 4 + i;
        if (r >= N_NODES) continue;
#pragma unroll
        for (int j = 0; j < 4; ++j) {
            int c = tc * 4 + j;
            C[(size_t)r * 64 + c] = acc[i][j] + b[c];
        }
    }
}

// ---------------- Edge pass: one wave (64 lanes) per edge ----------------
template <int H>  // D = 64/H
__global__ __launch_bounds__(256) void edge_pass(const int* __restrict__ ei,
                                                 const float* __restrict__ q,
                                                 const float* __restrict__ k,
                                                 const float* __restrict__ v,
                                                 float* __restrict__ agg,
                                                 float* __restrict__ den) {
    const int D = 64 / H;
    const int lane = threadIdx.x & 63;
    const int e = (blockIdx.x * 256 + threadIdx.x) >> 6;
    if (e >= N_EDGES) return;
    const int src = ei[e];              // (2,E) blocks: [src | dst]
    const int dst = ei[N_EDGES + e];
    if ((unsigned)src >= N_NODES || (unsigned)dst >= N_NODES) return;

    float p = q[(size_t)dst * 64 + lane] * k[(size_t)src * 64 + lane];
#pragma unroll
    for (int off = 1; off < D; off <<= 1) p += __shfl_xor(p, off, 64);

    const float ex = expf(p * (D == 16 ? 0.25f : 0.125f));  // 1/sqrt(D)

    if ((lane & (D - 1)) == 0) atomicAdd(den + (size_t)dst * H + (lane / D), ex);
    atomicAdd(agg + (size_t)dst * 64 + lane, ex * v[(size_t)src * 64 + lane]);
}

// ---------------- Finalize ----------------
__global__ __launch_bounds__(256) void finalize1(const float* __restrict__ agg,
                                                 const float* __restrict__ den,
                                                 const float* __restrict__ s,
                                                 float* __restrict__ h) {
    int i = blockIdx.x * 256 + threadIdx.x;
    if (i >= N_NODES * 64) return;
    int n = i >> 6;
    int hd = (i & 63) >> 4;  // head (H=4, D=16), h-major concat
    float dn = den[(size_t)n * 4 + hd];
    float a = (dn != 0.f) ? (agg[i] / dn) : 0.f;
    h[i] = fmaxf(a + s[i], 0.f);
}

__global__ __launch_bounds__(256) void finalize2(const float* __restrict__ agg,
                                                 const float* __restrict__ den,
                                                 const float* __restrict__ s,
                                                 float* __restrict__ out) {
    int i = blockIdx.x * 256 + threadIdx.x;
    if (i >= N_NODES * 64) return;
    int n = i >> 6;
    float dn = den[n];
    float a = (dn != 0.f) ? (agg[i] / dn) : 0.f;
    out[i] = a + s[i];   // FLOAT32 output
}

extern "C" void kernel_launch(void* const* d_in, const int* in_sizes, int n_in,
                              void* d_out, int out_size, void* d_ws, size_t ws_size,
                              hipStream_t stream) {
    const float* x   = (const float*)d_in[0];
    const int*   ei  = (const int*)d_in[1];
    const float* Wq1 = (const float*)d_in[2];
    const float* bq1 = (const float*)d_in[3];
    const float* Wk1 = (const float*)d_in[4];
    const float* bk1 = (const float*)d_in[5];
    const float* Wv1 = (const float*)d_in[6];
    const float* bv1 = (const float*)d_in[7];
    const float* Ws1 = (const float*)d_in[8];
    const float* bs1 = (const float*)d_in[9];
    const float* Wq2 = (const float*)d_in[10];
    const float* bq2 = (const float*)d_in[11];
    const float* Wk2 = (const float*)d_in[12];
    const float* bk2 = (const float*)d_in[13];
    const float* Wv2 = (const float*)d_in[14];
    const float* bv2 = (const float*)d_in[15];
    const float* Ws2 = (const float*)d_in[16];
    const float* bs2 = (const float*)d_in[17];

    const size_t N = N_NODES;
    float* q   = (float*)d_ws;      // N*64
    float* k   = q + N * 64;        // N*64
    float* v   = k + N * 64;        // N*64
    float* s   = v + N * 64;        // N*64 (skip)
    float* agg = s + N * 64;        // N*64
    float* den = agg + N * 64;      // N*4 (contiguous after agg for one memset)
    float* h   = den + N * 4;       // N*64
    // total 78.4 MB (r2 used this exact layout; r2==r4 bit-exact values => OK)

    const int gemmGrid = (N_NODES + 63) / 64;
    const int edgeGrid = (N_EDGES * 64 + 255) / 256;
    const int finGrid  = (N_NODES * 64 + 255) / 256;

    // ---------------- Layer 1 ----------------
    gemm_proj<<<gemmGrid, 256, 0, stream>>>(x, 128, Wq1, bq1, q);
    gemm_proj<<<gemmGrid, 256, 0, stream>>>(x, 128, Wk1, bk1, k);
    gemm_proj<<<gemmGrid, 256, 0, stream>>>(x, 128, Wv1, bv1, v);
    gemm_proj<<<gemmGrid, 256, 0, stream>>>(x, 128, Ws1, bs1, s);
    hipMemsetAsync(agg, 0, N * 68 * sizeof(float), stream);
    edge_pass<4><<<edgeGrid, 256, 0, stream>>>(ei, q, k, v, agg, den);
    finalize1<<<finGrid, 256, 0, stream>>>(agg, den, s, h);

    // ---------------- Layer 2 ----------------
    gemm_proj<<<gemmGrid, 256, 0, stream>>>(h, 64, Wq2, bq2, q);
    gemm_proj<<<gemmGrid, 256, 0, stream>>>(h, 64, Wk2, bk2, k);
    gemm_proj<<<gemmGrid, 256, 0, stream>>>(h, 64, Wv2, bv2, v);
    gemm_proj<<<gemmGrid, 256, 0, stream>>>(h, 64, Ws2, bs2, s);
    hipMemsetAsync(agg, 0, N * 68 * sizeof(float), stream);
    edge_pass<1><<<edgeGrid, 256, 0, stream>>>(ei, q, k, v, agg, den);
    finalize2<<<finGrid, 256, 0, stream>>>(agg, den, s, (float*)d_out);
}

// Round 13
// 690.253 us; speedup vs baseline: 1.1081x; 1.1081x over previous
//
#include <hip/hip_runtime.h>
#include <hip/hip_bf16.h>

// ROUND 13 (first optimization round; r12 passed at 765 us, absmax 0.0039).
// Changes vs r12, all targeting the dominant edge passes (2x233 us, 225 MB
// atomic write traffic each):
//   1) device-built CSR (histogram -> 1-block scan -> scatter), shared by both
//      layers; aggregation = one wave per dst node, Sum(ex*v)/Sum(ex) in
//      registers -> zero atomics, no agg/den buffers or memsets.
//   2) q/k/v stored bf16 (GEMM epilogue converts) -> half gather bytes.
//   3) finalize fused into aggregation epilogue (+skip, relu, store).
// Output fp32 (root cause of r2-r11 established: d_out is float*).

#define N_NODES 50000
#define N_EDGES 800000

using bf16 = __hip_bfloat16;

__device__ __forceinline__ void storev(float* p, float v) { *p = v; }
__device__ __forceinline__ void storev(bf16* p, float v) { *p = __float2bfloat16(v); }

// ---------------- GEMM: C[N x 64] = A[N x K] * W[64 x K]^T + b ----------------
template <typename CT>
__global__ __launch_bounds__(256) void gemm_proj(const float* __restrict__ A, int K,
                                                 const float* __restrict__ W,
                                                 const float* __restrict__ b,
                                                 CT* __restrict__ C) {
    __shared__ float As[64][33];
    __shared__ float Ws[64][33];
    const int row0 = blockIdx.x * 64;
    const int tid = threadIdx.x;
    const int tr = tid >> 4;      // 0..15
    const int tc = tid & 15;      // 0..15
    float acc[4][4] = {};

    for (int k0 = 0; k0 < K; k0 += 32) {
        for (int i = tid; i < 64 * 32; i += 256) {
            int r = i >> 5, kk = i & 31;
            int gr = row0 + r;
            As[r][kk] = (gr < N_NODES) ? A[(size_t)gr * K + k0 + kk] : 0.f;
            Ws[r][kk] = W[(size_t)r * K + k0 + kk];
        }
        __syncthreads();
#pragma unroll 8
        for (int kk = 0; kk < 32; ++kk) {
            float a[4], w[4];
#pragma unroll
            for (int i = 0; i < 4; ++i) a[i] = As[tr * 4 + i][kk];
#pragma unroll
            for (int j = 0; j < 4; ++j) w[j] = Ws[tc * 4 + j][kk];
#pragma unroll
            for (int i = 0; i < 4; ++i)
#pragma unroll
                for (int j = 0; j < 4; ++j) acc[i][j] += a[i] * w[j];
        }
        __syncthreads();
    }
#pragma unroll
    for (int i = 0; i < 4; ++i) {
        int r = row0 + tr * 4 + i;
        if (r >= N_NODES) continue;
#pragma unroll
        for (int j = 0; j < 4; ++j) {
            int c = tc * 4 + j;
            storev(C + (size_t)r * 64 + c, acc[i][j] + b[c]);
        }
    }
}

// ---------------- CSR build ----------------
__global__ __launch_bounds__(256) void hist_dst(const int* __restrict__ ei,
                                                int* __restrict__ deg) {
    int e = blockIdx.x * 256 + threadIdx.x;
    if (e >= N_EDGES) return;
    int d = ei[N_EDGES + e];
    if ((unsigned)d < N_NODES) atomicAdd(&deg[d], 1);
}

__global__ __launch_bounds__(256) void scan_deg(const int* __restrict__ deg,
                                                int* __restrict__ off,
                                                int* __restrict__ cursor) {
    __shared__ int part[256];
    const int t = threadIdx.x;
    const int CH = (N_NODES + 255) / 256;  // 196
    int lo = t * CH, hi = min(lo + CH, N_NODES);
    int s = 0;
    for (int i = lo; i < hi; ++i) s += deg[i];
    part[t] = s;
    __syncthreads();
    for (int st = 1; st < 256; st <<= 1) {
        int v = (t >= st) ? part[t - st] : 0;
        __syncthreads();
        part[t] += v;
        __syncthreads();
    }
    int run = (t == 0) ? 0 : part[t - 1];  // exclusive prefix
    for (int i = lo; i < hi; ++i) {
        off[i] = run;
        cursor[i] = run;
        run += deg[i];
    }
    if (t == 255) off[N_NODES] = run;
}

__global__ __launch_bounds__(256) void scatter_src(const int* __restrict__ ei,
                                                   int* __restrict__ cursor,
                                                   int* __restrict__ csr_src) {
    int e = blockIdx.x * 256 + threadIdx.x;
    if (e >= N_EDGES) return;
    int s = ei[e];
    int d = ei[N_EDGES + e];
    if ((unsigned)s >= N_NODES || (unsigned)d >= N_NODES) return;
    int pos = atomicAdd(&cursor[d], 1);
    csr_src[pos] = s;
}

// ------------- Aggregation: one wave per dst node, fused finalize -----------
template <int H, bool RELU>  // D = 64/H
__global__ __launch_bounds__(256) void agg_csr(const int* __restrict__ off,
                                               const int* __restrict__ csr_src,
                                               const bf16* __restrict__ qb,
                                               const bf16* __restrict__ kb,
                                               const bf16* __restrict__ vb,
                                               const float* __restrict__ s,
                                               float* __restrict__ out) {
    const int D = 64 / H;
    const int lane = threadIdx.x & 63;
    const int n = (blockIdx.x * 256 + threadIdx.x) >> 6;
    if (n >= N_NODES) return;

    const float qv = __bfloat162float(qb[(size_t)n * 64 + lane]);
    float acc = 0.f, dsum = 0.f;
    const int j1 = off[n + 1];
    for (int j = off[n]; j < j1; ++j) {
        int sidx = csr_src[j];
        float kv = __bfloat162float(kb[(size_t)sidx * 64 + lane]);
        float vv = __bfloat162float(vb[(size_t)sidx * 64 + lane]);
        float p = qv * kv;
#pragma unroll
        for (int o = 1; o < D; o <<= 1) p += __shfl_xor(p, o, 64);
        float ex = __expf(p * (D == 16 ? 0.25f : 0.125f));
        acc += ex * vv;
        dsum += ex;
    }
    float a = (dsum != 0.f) ? acc / dsum : 0.f;
    float val = a + s[(size_t)n * 64 + lane];
    if (RELU) val = fmaxf(val, 0.f);
    out[(size_t)n * 64 + lane] = val;
}

extern "C" void kernel_launch(void* const* d_in, const int* in_sizes, int n_in,
                              void* d_out, int out_size, void* d_ws, size_t ws_size,
                              hipStream_t stream) {
    const float* x   = (const float*)d_in[0];
    const int*   ei  = (const int*)d_in[1];
    const float* Wq1 = (const float*)d_in[2];
    const float* bq1 = (const float*)d_in[3];
    const float* Wk1 = (const float*)d_in[4];
    const float* bk1 = (const float*)d_in[5];
    const float* Wv1 = (const float*)d_in[6];
    const float* bv1 = (const float*)d_in[7];
    const float* Ws1 = (const float*)d_in[8];
    const float* bs1 = (const float*)d_in[9];
    const float* Wq2 = (const float*)d_in[10];
    const float* bq2 = (const float*)d_in[11];
    const float* Wk2 = (const float*)d_in[12];
    const float* bk2 = (const float*)d_in[13];
    const float* Wv2 = (const float*)d_in[14];
    const float* bv2 = (const float*)d_in[15];
    const float* Ws2 = (const float*)d_in[16];
    const float* bs2 = (const float*)d_in[17];

    const size_t N = N_NODES;
    float* s   = (float*)d_ws;            // N*64 fp32 (skip)
    float* h   = s + N * 64;              // N*64 fp32 (layer-1 out)
    bf16*  qb  = (bf16*)(h + N * 64);     // N*64 bf16
    bf16*  kb  = qb + N * 64;
    bf16*  vb  = kb + N * 64;
    int*   deg = (int*)(vb + N * 64);     // N
    int*   off = deg + N_NODES;           // N+1
    int*   cur = off + N_NODES + 1;       // N
    int*   csr = cur + N_NODES;           // E
    // total ~48.6 MB (r12 passed with 78.4 MB => ws_size sufficient)

    const int gemmGrid = (N_NODES + 63) / 64;
    const int edgeGrid = (N_EDGES + 255) / 256;
    const int aggGrid  = (N_NODES * 64 + 255) / 256;

    // ---------------- CSR build (shared by both layers) ----------------
    hipMemsetAsync(deg, 0, N_NODES * sizeof(int), stream);
    hist_dst<<<edgeGrid, 256, 0, stream>>>(ei, deg);
    scan_deg<<<1, 256, 0, stream>>>(deg, off, cur);
    scatter_src<<<edgeGrid, 256, 0, stream>>>(ei, cur, csr);

    // ---------------- Layer 1 ----------------
    gemm_proj<bf16><<<gemmGrid, 256, 0, stream>>>(x, 128, Wq1, bq1, qb);
    gemm_proj<bf16><<<gemmGrid, 256, 0, stream>>>(x, 128, Wk1, bk1, kb);
    gemm_proj<bf16><<<gemmGrid, 256, 0, stream>>>(x, 128, Wv1, bv1, vb);
    gemm_proj<float><<<gemmGrid, 256, 0, stream>>>(x, 128, Ws1, bs1, s);
    agg_csr<4, true><<<aggGrid, 256, 0, stream>>>(off, csr, qb, kb, vb, s, h);

    // ---------------- Layer 2 ----------------
    gemm_proj<bf16><<<gemmGrid, 256, 0, stream>>>(h, 64, Wq2, bq2, qb);
    gemm_proj<bf16><<<gemmGrid, 256, 0, stream>>>(h, 64, Wk2, bk2, kb);
    gemm_proj<bf16><<<gemmGrid, 256, 0, stream>>>(h, 64, Wv2, bv2, vb);
    gemm_proj<float><<<gemmGrid, 256, 0, stream>>>(h, 64, Ws2, bs2, s);
    agg_csr<1, false><<<aggGrid, 256, 0, stream>>>(off, csr, qb, kb, vb, s, (float*)d_out);
}

// Round 14
// 498.660 us; speedup vs baseline: 1.5338x; 1.3842x over previous
//
#include <hip/hip_runtime.h>
#include <hip/hip_bf16.h>

// ROUND 14. r13 = 690 us. Profile: scan_deg single-block scan = 121 us (1 CU
// utilized!) was #1 dispatch. Changes:
//  1) parallel 3-kernel scan (196-blk local scan -> 1-blk scan of sums ->
//     add offsets): 121 -> ~8 us.
//  2) per-layer fused q/k/v/skip GEMM (shared A-tile, k-major LDS so
//     fragment reads are ds_read_b128): 8 dispatches -> 2, A traffic /4.
//  3) agg_csr 2-edge unroll (two independent shuffle-reduce chains, ILP=2).
// Output fp32; q/k/v bf16 (absmax 0.0039 at threshold 0.019).

#define N_NODES 50000
#define N_EDGES 800000
#define NB_SCAN 196  // ceil(50000/256)

using bf16 = __hip_bfloat16;

// ---------------- Fused GEMM: 4 outputs share the A tile ----------------
// C_w[N,64] = A[N,K] @ W_w[64,K]^T + b_w ; q,k,v -> bf16, s -> fp32
template <int K>
__global__ __launch_bounds__(256) void gemm_qkvs(
    const float* __restrict__ A,
    const float* __restrict__ Wq, const float* __restrict__ Wk,
    const float* __restrict__ Wv, const float* __restrict__ Ws,
    const float* __restrict__ bq, const float* __restrict__ bk,
    const float* __restrict__ bv, const float* __restrict__ bs,
    bf16* __restrict__ qb, bf16* __restrict__ kb, bf16* __restrict__ vb,
    float* __restrict__ s) {
    __shared__ float As[32][65];       // k-major: As[kk][r], pad 65
    __shared__ float Wt[4][32][65];    // Wt[w][kk][c]
    const float* Wp[4] = {Wq, Wk, Wv, Ws};
    const int row0 = blockIdx.x * 64;
    const int tid = threadIdx.x;
    const int tr = tid >> 4;   // 0..15
    const int tc = tid & 15;   // 0..15
    float acc[4][4][4] = {};   // [w][i][j]

    for (int k0 = 0; k0 < K; k0 += 32) {
        for (int i = tid; i < 64 * 32; i += 256) {
            int r = i >> 5, kk = i & 31;
            int gr = row0 + r;
            As[kk][r] = (gr < N_NODES) ? A[(size_t)gr * K + k0 + kk] : 0.f;
        }
#pragma unroll
        for (int w = 0; w < 4; ++w)
            for (int i = tid; i < 64 * 32; i += 256) {
                int c = i >> 5, kk = i & 31;
                Wt[w][kk][c] = Wp[w][(size_t)c * K + k0 + kk];
            }
        __syncthreads();
#pragma unroll 4
        for (int kk = 0; kk < 32; ++kk) {
            float a[4];
#pragma unroll
            for (int i = 0; i < 4; ++i) a[i] = As[kk][tr * 4 + i];  // b128
#pragma unroll
            for (int w = 0; w < 4; ++w) {
                float wv[4];
#pragma unroll
                for (int j = 0; j < 4; ++j) wv[j] = Wt[w][kk][tc * 4 + j];  // b128
#pragma unroll
                for (int i = 0; i < 4; ++i)
#pragma unroll
                    for (int j = 0; j < 4; ++j) acc[w][i][j] += a[i] * wv[j];
            }
        }
        __syncthreads();
    }
#pragma unroll
    for (int i = 0; i < 4; ++i) {
        int r = row0 + tr * 4 + i;
        if (r >= N_NODES) continue;
#pragma unroll
        for (int j = 0; j < 4; ++j) {
            int c = tc * 4 + j;
            size_t idx = (size_t)r * 64 + c;
            qb[idx] = __float2bfloat16(acc[0][i][j] + bq[c]);
            kb[idx] = __float2bfloat16(acc[1][i][j] + bk[c]);
            vb[idx] = __float2bfloat16(acc[2][i][j] + bv[c]);
            s[idx]  = acc[3][i][j] + bs[c];
        }
    }
}

// ---------------- CSR build ----------------
__global__ __launch_bounds__(256) void hist_dst(const int* __restrict__ ei,
                                                int* __restrict__ deg) {
    int e = blockIdx.x * 256 + threadIdx.x;
    if (e >= N_EDGES) return;
    atomicAdd(&deg[ei[N_EDGES + e]], 1);
}

// local exclusive scan per 256-block + block sums
__global__ __launch_bounds__(256) void scan1(const int* __restrict__ deg,
                                             int* __restrict__ off,
                                             int* __restrict__ bsum) {
    __shared__ int sm[256];
    int i = blockIdx.x * 256 + threadIdx.x;
    int v = (i < N_NODES) ? deg[i] : 0;
    sm[threadIdx.x] = v;
    __syncthreads();
    for (int st = 1; st < 256; st <<= 1) {
        int t = (threadIdx.x >= (unsigned)st) ? sm[threadIdx.x - st] : 0;
        __syncthreads();
        sm[threadIdx.x] += t;
        __syncthreads();
    }
    if (i < N_NODES) off[i] = sm[threadIdx.x] - v;  // local exclusive
    if (threadIdx.x == 255) bsum[blockIdx.x] = sm[255];
}

// scan the 196 block sums (1 block); boff[NB_SCAN] = grand total
__global__ __launch_bounds__(256) void scan2(const int* __restrict__ bsum,
                                             int* __restrict__ boff) {
    __shared__ int sm[256];
    int b = threadIdx.x;
    int v = (b < NB_SCAN) ? bsum[b] : 0;
    sm[b] = v;
    __syncthreads();
    for (int st = 1; st < 256; st <<= 1) {
        int t = (b >= st) ? sm[b - st] : 0;
        __syncthreads();
        sm[b] += t;
        __syncthreads();
    }
    if (b < NB_SCAN) boff[b] = sm[b] - v;
    if (b == 255) boff[NB_SCAN] = sm[255];
}

__global__ __launch_bounds__(256) void scan3(int* __restrict__ off,
                                             const int* __restrict__ boff,
                                             int* __restrict__ cursor) {
    int i = blockIdx.x * 256 + threadIdx.x;
    if (i < N_NODES) {
        int v = off[i] + boff[blockIdx.x];
        off[i] = v;
        cursor[i] = v;
    }
    if (i == 0) off[N_NODES] = boff[NB_SCAN];
}

__global__ __launch_bounds__(256) void scatter_src(const int* __restrict__ ei,
                                                   int* __restrict__ cursor,
                                                   int* __restrict__ csr_src) {
    int e = blockIdx.x * 256 + threadIdx.x;
    if (e >= N_EDGES) return;
    int pos = atomicAdd(&cursor[ei[N_EDGES + e]], 1);
    csr_src[pos] = ei[e];
}

// ------------- Aggregation: one wave per dst node, fused finalize -----------
template <int H, bool RELU>  // D = 64/H
__global__ __launch_bounds__(256) void agg_csr(const int* __restrict__ off,
                                               const int* __restrict__ csr_src,
                                               const bf16* __restrict__ qb,
                                               const bf16* __restrict__ kb,
                                               const bf16* __restrict__ vb,
                                               const float* __restrict__ s,
                                               float* __restrict__ out) {
    const int D = 64 / H;
    const float scale = (D == 16) ? 0.25f : 0.125f;
    const int lane = threadIdx.x & 63;
    const int n = (blockIdx.x * 256 + threadIdx.x) >> 6;
    if (n >= N_NODES) return;

    const float qv = __bfloat162float(qb[(size_t)n * 64 + lane]);
    float acc = 0.f, dsum = 0.f;
    int j = off[n];
    const int j1 = off[n + 1];
    for (; j + 1 < j1; j += 2) {   // 2-edge unroll: independent reduce chains
        int s0 = csr_src[j], s1 = csr_src[j + 1];
        float k0 = __bfloat162float(kb[(size_t)s0 * 64 + lane]);
        float v0 = __bfloat162float(vb[(size_t)s0 * 64 + lane]);
        float k1 = __bfloat162float(kb[(size_t)s1 * 64 + lane]);
        float v1 = __bfloat162float(vb[(size_t)s1 * 64 + lane]);
        float p0 = qv * k0, p1 = qv * k1;
#pragma unroll
        for (int o = 1; o < D; o <<= 1) {
            p0 += __shfl_xor(p0, o, 64);
            p1 += __shfl_xor(p1, o, 64);
        }
        float e0 = __expf(p0 * scale), e1 = __expf(p1 * scale);
        acc += e0 * v0 + e1 * v1;
        dsum += e0 + e1;
    }
    if (j < j1) {
        int s0 = csr_src[j];
        float k0 = __bfloat162float(kb[(size_t)s0 * 64 + lane]);
        float v0 = __bfloat162float(vb[(size_t)s0 * 64 + lane]);
        float p0 = qv * k0;
#pragma unroll
        for (int o = 1; o < D; o <<= 1) p0 += __shfl_xor(p0, o, 64);
        float e0 = __expf(p0 * scale);
        acc += e0 * v0;
        dsum += e0;
    }
    float a = (dsum != 0.f) ? acc / dsum : 0.f;
    float val = a + s[(size_t)n * 64 + lane];
    if (RELU) val = fmaxf(val, 0.f);
    out[(size_t)n * 64 + lane] = val;
}

extern "C" void kernel_launch(void* const* d_in, const int* in_sizes, int n_in,
                              void* d_out, int out_size, void* d_ws, size_t ws_size,
                              hipStream_t stream) {
    const float* x   = (const float*)d_in[0];
    const int*   ei  = (const int*)d_in[1];
    const float* Wq1 = (const float*)d_in[2];
    const float* bq1 = (const float*)d_in[3];
    const float* Wk1 = (const float*)d_in[4];
    const float* bk1 = (const float*)d_in[5];
    const float* Wv1 = (const float*)d_in[6];
    const float* bv1 = (const float*)d_in[7];
    const float* Ws1 = (const float*)d_in[8];
    const float* bs1 = (const float*)d_in[9];
    const float* Wq2 = (const float*)d_in[10];
    const float* bq2 = (const float*)d_in[11];
    const float* Wk2 = (const float*)d_in[12];
    const float* bk2 = (const float*)d_in[13];
    const float* Wv2 = (const float*)d_in[14];
    const float* bv2 = (const float*)d_in[15];
    const float* Ws2 = (const float*)d_in[16];
    const float* bs2 = (const float*)d_in[17];

    const size_t N = N_NODES;
    float* s    = (float*)d_ws;            // N*64 fp32 (skip)
    float* h    = s + N * 64;              // N*64 fp32
    bf16*  qb   = (bf16*)(h + N * 64);     // N*64 bf16
    bf16*  kb   = qb + N * 64;
    bf16*  vb   = kb + N * 64;
    int*   deg  = (int*)(vb + N * 64);     // N
    int*   off  = deg + N_NODES;           // N+1
    int*   cur  = off + N_NODES + 1;       // N
    int*   bsum = cur + N_NODES;           // NB_SCAN
    int*   boff = bsum + NB_SCAN;          // NB_SCAN+1
    int*   csr  = boff + NB_SCAN + 1;      // E

    const int gemmGrid = (N_NODES + 63) / 64;
    const int edgeGrid = (N_EDGES + 255) / 256;
    const int nodeGrid = NB_SCAN;          // ceil(N/256)
    const int aggGrid  = (N_NODES * 64 + 255) / 256;

    // ---------------- CSR build (shared by both layers) ----------------
    hipMemsetAsync(deg, 0, N_NODES * sizeof(int), stream);
    hist_dst<<<edgeGrid, 256, 0, stream>>>(ei, deg);
    scan1<<<nodeGrid, 256, 0, stream>>>(deg, off, bsum);
    scan2<<<1, 256, 0, stream>>>(bsum, boff);
    scan3<<<nodeGrid, 256, 0, stream>>>(off, boff, cur);
    scatter_src<<<edgeGrid, 256, 0, stream>>>(ei, cur, csr);

    // ---------------- Layer 1 ----------------
    gemm_qkvs<128><<<gemmGrid, 256, 0, stream>>>(x, Wq1, Wk1, Wv1, Ws1,
                                                 bq1, bk1, bv1, bs1, qb, kb, vb, s);
    agg_csr<4, true><<<aggGrid, 256, 0, stream>>>(off, csr, qb, kb, vb, s, h);

    // ---------------- Layer 2 ----------------
    gemm_qkvs<64><<<gemmGrid, 256, 0, stream>>>(h, Wq2, Wk2, Wv2, Ws2,
                                                bq2, bk2, bv2, bs2, qb, kb, vb, s);
    agg_csr<1, false><<<aggGrid, 256, 0, stream>>>(off, csr, qb, kb, vb, s, (float*)d_out);
}

// Round 15
// 383.374 us; speedup vs baseline: 1.9951x; 1.3007x over previous
//
#include <hip/hip_runtime.h>
#include <hip/hip_bf16.h>

// ROUND 15. r14 = 499 us; gemm_qkvs (fp32 VALU + 9.6M LDS bank conflicts,
// 19% occupancy) was 2x135 us. Replace with LDS-free bf16 MFMA GEMM
// (16x16x32, m92-verified B^T fragment pattern): per-block 4 waves, wave w
// computes 64x64 for weight matrix w; A-frags/B-frags via direct 16B global
// loads (A tile L1-resident, W L2-hot). x/W converted to bf16 up front
// (precision budget: absmax 0.0039 -> ~0.008, threshold 0.019).
// agg_csr: 4-edge unroll; layer-1 agg writes h as bf16 for layer-2 GEMM.

#define N_NODES 50000
#define N_EDGES 800000
#define NB_SCAN 196   // ceil(50000/256)
#define NPAD    50048 // 782*64, padded row count for unguarded frag loads

using bf16 = __hip_bfloat16;
typedef __attribute__((ext_vector_type(8))) short bf16x8;  // 8 bf16 = 4 VGPRs
typedef __attribute__((ext_vector_type(4))) float f32x4;

__device__ __forceinline__ void storev(float* p, float v) { *p = v; }
__device__ __forceinline__ void storev(bf16* p, float v) { *p = __float2bfloat16(v); }

// ---------------- fp32 -> bf16 converters ----------------
__global__ __launch_bounds__(256) void conv_x(const float* __restrict__ src,
                                              bf16* __restrict__ dst, int n) {
    for (int i = blockIdx.x * 256 + threadIdx.x; i < n; i += gridDim.x * 256)
        dst[i] = __float2bfloat16(src[i]);
}

struct WPtrs { const float* p[8]; };
// 8 weight buffers -> packed wb: layer1 4x8192 at [0], layer2 4x4096 at [32768]
__global__ __launch_bounds__(256) void conv_w(WPtrs wp, bf16* __restrict__ wb) {
    int y = blockIdx.y;
    int len = (y < 4) ? 8192 : 4096;
    int base = (y < 4) ? y * 8192 : 32768 + (y - 4) * 4096;
    for (int i = blockIdx.x * 256 + threadIdx.x; i < len; i += gridDim.x * 256)
        wb[base + i] = __float2bfloat16(wp.p[y][i]);
}

// ---------------- MFMA GEMM: 4 weight mats share A ----------------
// A[NPAD x K] bf16 row-major; W w-th mat at wb + w*64*K, [64 x K] row-major.
// C_w[n,c] = sum_k A[n,k] * W_w[c,k] + b_w[c]. Wave w -> matrix w.
template <int K>
__global__ __launch_bounds__(256) void gemm4_mfma(
    const bf16* __restrict__ A, const bf16* __restrict__ wb,
    const float* __restrict__ bq, const float* __restrict__ bk,
    const float* __restrict__ bv, const float* __restrict__ bs,
    bf16* __restrict__ qb, bf16* __restrict__ kb, bf16* __restrict__ vb,
    float* __restrict__ s) {
    const int wave = threadIdx.x >> 6;
    const int lane = threadIdx.x & 63;
    const int row0 = blockIdx.x * 64;
    const int m  = lane & 15;   // A row / B row within 16-tile
    const int kg = lane >> 4;   // k-group: 8 bf16 each
    const bf16* W = wb + (size_t)wave * 64 * K;

    f32x4 acc[4][4];
#pragma unroll
    for (int i = 0; i < 4; ++i)
#pragma unroll
        for (int j = 0; j < 4; ++j) acc[i][j] = (f32x4){0.f, 0.f, 0.f, 0.f};

#pragma unroll
    for (int k0 = 0; k0 < K; k0 += 32) {
        bf16x8 a[4], b[4];
#pragma unroll
        for (int i = 0; i < 4; ++i)
            a[i] = *(const bf16x8*)(A + (size_t)(row0 + i * 16 + m) * K + k0 + kg * 8);
#pragma unroll
        for (int j = 0; j < 4; ++j)
            b[j] = *(const bf16x8*)(W + (size_t)(j * 16 + m) * K + k0 + kg * 8);
#pragma unroll
        for (int i = 0; i < 4; ++i)
#pragma unroll
            for (int j = 0; j < 4; ++j)
                acc[i][j] = __builtin_amdgcn_mfma_f32_16x16x32_bf16(a[i], b[j], acc[i][j], 0, 0, 0);
    }

    // epilogue: C layout col=lane&15, row=(lane>>4)*4+reg (m89/m91 verified)
    const int crow = (lane >> 4) * 4;
    const int ccol = lane & 15;
    const float* B = (wave == 0) ? bq : (wave == 1) ? bk : (wave == 2) ? bv : bs;
    float bias[4];
#pragma unroll
    for (int j = 0; j < 4; ++j) bias[j] = B[j * 16 + ccol];

#pragma unroll
    for (int i = 0; i < 4; ++i)
#pragma unroll
        for (int r = 0; r < 4; ++r) {
            int gr = row0 + i * 16 + crow + r;
            if (gr >= N_NODES) continue;
#pragma unroll
            for (int j = 0; j < 4; ++j) {
                float val = acc[i][j][r] + bias[j];
                size_t idx = (size_t)gr * 64 + j * 16 + ccol;
                if (wave == 0) storev(qb + idx, val);
                else if (wave == 1) storev(kb + idx, val);
                else if (wave == 2) storev(vb + idx, val);
                else storev(s + idx, val);
            }
        }
}

// ---------------- CSR build ----------------
__global__ __launch_bounds__(256) void hist_dst(const int* __restrict__ ei,
                                                int* __restrict__ deg) {
    int e = blockIdx.x * 256 + threadIdx.x;
    if (e >= N_EDGES) return;
    atomicAdd(&deg[ei[N_EDGES + e]], 1);
}

__global__ __launch_bounds__(256) void scan1(const int* __restrict__ deg,
                                             int* __restrict__ off,
                                             int* __restrict__ bsum) {
    __shared__ int sm[256];
    int i = blockIdx.x * 256 + threadIdx.x;
    int v = (i < N_NODES) ? deg[i] : 0;
    sm[threadIdx.x] = v;
    __syncthreads();
    for (int st = 1; st < 256; st <<= 1) {
        int t = (threadIdx.x >= (unsigned)st) ? sm[threadIdx.x - st] : 0;
        __syncthreads();
        sm[threadIdx.x] += t;
        __syncthreads();
    }
    if (i < N_NODES) off[i] = sm[threadIdx.x] - v;
    if (threadIdx.x == 255) bsum[blockIdx.x] = sm[255];
}

__global__ __launch_bounds__(256) void scan2(const int* __restrict__ bsum,
                                             int* __restrict__ boff) {
    __shared__ int sm[256];
    int b = threadIdx.x;
    int v = (b < NB_SCAN) ? bsum[b] : 0;
    sm[b] = v;
    __syncthreads();
    for (int st = 1; st < 256; st <<= 1) {
        int t = (b >= st) ? sm[b - st] : 0;
        __syncthreads();
        sm[b] += t;
        __syncthreads();
    }
    if (b < NB_SCAN) boff[b] = sm[b] - v;
    if (b == 255) boff[NB_SCAN] = sm[255];
}

__global__ __launch_bounds__(256) void scan3(int* __restrict__ off,
                                             const int* __restrict__ boff,
                                             int* __restrict__ cursor) {
    int i = blockIdx.x * 256 + threadIdx.x;
    if (i < N_NODES) {
        int v = off[i] + boff[blockIdx.x];
        off[i] = v;
        cursor[i] = v;
    }
    if (i == 0) off[N_NODES] = boff[NB_SCAN];
}

__global__ __launch_bounds__(256) void scatter_src(const int* __restrict__ ei,
                                                   int* __restrict__ cursor,
                                                   int* __restrict__ csr_src) {
    int e = blockIdx.x * 256 + threadIdx.x;
    if (e >= N_EDGES) return;
    int pos = atomicAdd(&cursor[ei[N_EDGES + e]], 1);
    csr_src[pos] = ei[e];
}

// ------------- Aggregation: one wave per dst node, 4-edge unroll -----------
template <int H, bool RELU, typename OT>  // D = 64/H
__global__ __launch_bounds__(256) void agg_csr(const int* __restrict__ off,
                                               const int* __restrict__ csr_src,
                                               const bf16* __restrict__ qb,
                                               const bf16* __restrict__ kb,
                                               const bf16* __restrict__ vb,
                                               const float* __restrict__ s,
                                               OT* __restrict__ out) {
    const int D = 64 / H;
    const float scale = (D == 16) ? 0.25f : 0.125f;
    const int lane = threadIdx.x & 63;
    const int n = (blockIdx.x * 256 + threadIdx.x) >> 6;
    if (n >= N_NODES) return;

    const float qv = __bfloat162float(qb[(size_t)n * 64 + lane]);
    float acc = 0.f, dsum = 0.f;
    int j = off[n];
    const int j1 = off[n + 1];
    for (; j + 3 < j1; j += 4) {
        int s0 = csr_src[j], s1 = csr_src[j + 1], s2 = csr_src[j + 2], s3 = csr_src[j + 3];
        float k0 = __bfloat162float(kb[(size_t)s0 * 64 + lane]);
        float k1 = __bfloat162float(kb[(size_t)s1 * 64 + lane]);
        float k2 = __bfloat162float(kb[(size_t)s2 * 64 + lane]);
        float k3 = __bfloat162float(kb[(size_t)s3 * 64 + lane]);
        float v0 = __bfloat162float(vb[(size_t)s0 * 64 + lane]);
        float v1 = __bfloat162float(vb[(size_t)s1 * 64 + lane]);
        float v2 = __bfloat162float(vb[(size_t)s2 * 64 + lane]);
        float v3 = __bfloat162float(vb[(size_t)s3 * 64 + lane]);
        float p0 = qv * k0, p1 = qv * k1, p2 = qv * k2, p3 = qv * k3;
#pragma unroll
        for (int o = 1; o < D; o <<= 1) {
            p0 += __shfl_xor(p0, o, 64);
            p1 += __shfl_xor(p1, o, 64);
            p2 += __shfl_xor(p2, o, 64);
            p3 += __shfl_xor(p3, o, 64);
        }
        float e0 = __expf(p0 * scale), e1 = __expf(p1 * scale);
        float e2 = __expf(p2 * scale), e3 = __expf(p3 * scale);
        acc += e0 * v0 + e1 * v1 + e2 * v2 + e3 * v3;
        dsum += e0 + e1 + e2 + e3;
    }
    for (; j < j1; ++j) {
        int s0 = csr_src[j];
        float k0 = __bfloat162float(kb[(size_t)s0 * 64 + lane]);
        float v0 = __bfloat162float(vb[(size_t)s0 * 64 + lane]);
        float p0 = qv * k0;
#pragma unroll
        for (int o = 1; o < D; o <<= 1) p0 += __shfl_xor(p0, o, 64);
        float e0 = __expf(p0 * scale);
        acc += e0 * v0;
        dsum += e0;
    }
    float a = (dsum != 0.f) ? acc / dsum : 0.f;
    float val = a + s[(size_t)n * 64 + lane];
    if (RELU) val = fmaxf(val, 0.f);
    storev(out + (size_t)n * 64 + lane, val);
}

extern "C" void kernel_launch(void* const* d_in, const int* in_sizes, int n_in,
                              void* d_out, int out_size, void* d_ws, size_t ws_size,
                              hipStream_t stream) {
    const float* x  = (const float*)d_in[0];
    const int*   ei = (const int*)d_in[1];
    const float* bq1 = (const float*)d_in[3];
    const float* bk1 = (const float*)d_in[5];
    const float* bv1 = (const float*)d_in[7];
    const float* bs1 = (const float*)d_in[9];
    const float* bq2 = (const float*)d_in[11];
    const float* bk2 = (const float*)d_in[13];
    const float* bv2 = (const float*)d_in[15];
    const float* bs2 = (const float*)d_in[17];

    WPtrs wp;
    wp.p[0] = (const float*)d_in[2];   // Wq1
    wp.p[1] = (const float*)d_in[4];   // Wk1
    wp.p[2] = (const float*)d_in[6];   // Wv1
    wp.p[3] = (const float*)d_in[8];   // Ws1
    wp.p[4] = (const float*)d_in[10];  // Wq2
    wp.p[5] = (const float*)d_in[12];  // Wk2
    wp.p[6] = (const float*)d_in[14];  // Wv2
    wp.p[7] = (const float*)d_in[16];  // Ws2

    const size_t N = N_NODES;
    bf16* xb  = (bf16*)d_ws;                 // NPAD*128
    bf16* hb  = xb + (size_t)NPAD * 128;     // NPAD*64
    bf16* qb  = hb + (size_t)NPAD * 64;      // N*64
    bf16* kb  = qb + N * 64;                 // N*64
    bf16* vb  = kb + N * 64;                 // N*64
    bf16* wb  = vb + N * 64;                 // 49152 (4x8192 + 4x4096)
    float* s  = (float*)(wb + 49152);        // N*64 fp32
    int* deg  = (int*)(s + N * 64);          // N
    int* off  = deg + N_NODES;               // N+1
    int* cur  = off + N_NODES + 1;           // N
    int* bsum = cur + N_NODES;               // NB_SCAN
    int* boff = bsum + NB_SCAN;              // NB_SCAN+1
    int* csr  = boff + NB_SCAN + 1;          // E
    // ~53 MB total (78 MB established available in r12)

    const int gemmGrid = NPAD / 64;          // 782
    const int edgeGrid = (N_EDGES + 255) / 256;
    const int aggGrid  = (N_NODES * 64 + 255) / 256;

    // ---------------- CSR build + bf16 conversion ----------------
    hipMemsetAsync(deg, 0, N_NODES * sizeof(int), stream);
    hist_dst<<<edgeGrid, 256, 0, stream>>>(ei, deg);
    scan1<<<NB_SCAN, 256, 0, stream>>>(deg, off, bsum);
    scan2<<<1, 256, 0, stream>>>(bsum, boff);
    scan3<<<NB_SCAN, 256, 0, stream>>>(off, boff, cur);
    scatter_src<<<edgeGrid, 256, 0, stream>>>(ei, cur, csr);
    conv_x<<<1024, 256, 0, stream>>>(x, xb, N_NODES * 128);
    conv_w<<<dim3(32, 8), 256, 0, stream>>>(wp, wb);

    // ---------------- Layer 1 ----------------
    gemm4_mfma<128><<<gemmGrid, 256, 0, stream>>>(xb, wb, bq1, bk1, bv1, bs1,
                                                  qb, kb, vb, s);
    agg_csr<4, true, bf16><<<aggGrid, 256, 0, stream>>>(off, csr, qb, kb, vb, s, hb);

    // ---------------- Layer 2 ----------------
    gemm4_mfma<64><<<gemmGrid, 256, 0, stream>>>(hb, wb + 32768, bq2, bk2, bv2, bs2,
                                                 qb, kb, vb, s);
    agg_csr<1, false, float><<<aggGrid, 256, 0, stream>>>(off, csr, qb, kb, vb, s,
                                                          (float*)d_out);
}

// Round 16
// 370.187 us; speedup vs baseline: 2.0661x; 1.0356x over previous
//
#include <hip/hip_runtime.h>
#include <hip/hip_bf16.h>

// ROUND 16. r15 = 383 us; agg_csr 2x65.5 us now dominates (latency-bound
// gathers: VALU 54%, BW 20%). Changes:
//  1) k/v interleaved per channel in one u32 buffer -> ONE 4B/lane gather per
//     edge (was two 2B gathers) -> half the gather issue + dependency chains.
//  2) agg 8-edge unroll: 8 gathers in flight per wave.
//  3) conv_x/conv_w/hist fused into one 'prep' dispatch (blockIdx.y tasks).
// GEMM: bf16 MFMA 16x16x32, LDS-free (r15, verified). Output fp32.

#define N_NODES 50000
#define N_EDGES 800000
#define NB_SCAN 196   // ceil(50000/256)
#define NPAD    50048 // 782*64

using bf16 = __hip_bfloat16;
typedef __attribute__((ext_vector_type(8))) short bf16x8;
typedef __attribute__((ext_vector_type(4))) float f32x4;

__device__ __forceinline__ float b2f(unsigned short u) {
    unsigned int x = ((unsigned int)u) << 16;
    return __builtin_bit_cast(float, x);
}

struct WPtrs { const float* p[8]; };

// ---------------- fused prep: conv_x / conv_w / hist ----------------
__global__ __launch_bounds__(256) void prep(const float* __restrict__ x,
                                            bf16* __restrict__ xb,
                                            WPtrs wp, bf16* __restrict__ wb,
                                            const int* __restrict__ ei,
                                            int* __restrict__ deg) {
    const int gs = gridDim.x * 256;
    const int t0 = blockIdx.x * 256 + threadIdx.x;
    if (blockIdx.y == 0) {                       // x -> bf16
        for (int i = t0; i < N_NODES * 128; i += gs)
            xb[i] = __float2bfloat16(x[i]);
    } else if (blockIdx.y == 1) {                // W -> bf16 (packed)
        for (int i = t0; i < 49152; i += gs) {
            int y, o;
            if (i < 32768) { y = i >> 13; o = i & 8191; }
            else { y = 4 + ((i - 32768) >> 12); o = (i - 32768) & 4095; }
            wb[i] = __float2bfloat16(wp.p[y][o]);
        }
    } else {                                      // dst histogram
        for (int e = t0; e < N_EDGES; e += gs)
            atomicAdd(&deg[ei[N_EDGES + e]], 1);
    }
}

// ---------------- MFMA GEMM: 4 weight mats share A ----------------
// qb: bf16 q ; kvb: interleaved bf16 pairs kv[idx*2]=k, kv[idx*2+1]=v
template <int K>
__global__ __launch_bounds__(256) void gemm4_mfma(
    const bf16* __restrict__ A, const bf16* __restrict__ wb,
    const float* __restrict__ bq, const float* __restrict__ bk,
    const float* __restrict__ bv, const float* __restrict__ bs,
    bf16* __restrict__ qb, bf16* __restrict__ kvb, float* __restrict__ s) {
    const int wave = threadIdx.x >> 6;
    const int lane = threadIdx.x & 63;
    const int row0 = blockIdx.x * 64;
    const int m  = lane & 15;
    const int kg = lane >> 4;
    const bf16* W = wb + (size_t)wave * 64 * K;

    f32x4 acc[4][4];
#pragma unroll
    for (int i = 0; i < 4; ++i)
#pragma unroll
        for (int j = 0; j < 4; ++j) acc[i][j] = (f32x4){0.f, 0.f, 0.f, 0.f};

#pragma unroll
    for (int k0 = 0; k0 < K; k0 += 32) {
        bf16x8 a[4], b[4];
#pragma unroll
        for (int i = 0; i < 4; ++i)
            a[i] = *(const bf16x8*)(A + (size_t)(row0 + i * 16 + m) * K + k0 + kg * 8);
#pragma unroll
        for (int j = 0; j < 4; ++j)
            b[j] = *(const bf16x8*)(W + (size_t)(j * 16 + m) * K + k0 + kg * 8);
#pragma unroll
        for (int i = 0; i < 4; ++i)
#pragma unroll
            for (int j = 0; j < 4; ++j)
                acc[i][j] = __builtin_amdgcn_mfma_f32_16x16x32_bf16(a[i], b[j], acc[i][j], 0, 0, 0);
    }

    const int crow = (lane >> 4) * 4;
    const int ccol = lane & 15;
    const float* B = (wave == 0) ? bq : (wave == 1) ? bk : (wave == 2) ? bv : bs;
    float bias[4];
#pragma unroll
    for (int j = 0; j < 4; ++j) bias[j] = B[j * 16 + ccol];

#pragma unroll
    for (int i = 0; i < 4; ++i)
#pragma unroll
        for (int r = 0; r < 4; ++r) {
            int gr = row0 + i * 16 + crow + r;
            if (gr >= N_NODES) continue;
#pragma unroll
            for (int j = 0; j < 4; ++j) {
                float val = acc[i][j][r] + bias[j];
                size_t idx = (size_t)gr * 64 + j * 16 + ccol;
                if (wave == 0) qb[idx] = __float2bfloat16(val);
                else if (wave == 1) kvb[idx * 2] = __float2bfloat16(val);
                else if (wave == 2) kvb[idx * 2 + 1] = __float2bfloat16(val);
                else s[idx] = val;
            }
        }
}

// ---------------- CSR build ----------------
__global__ __launch_bounds__(256) void scan1(const int* __restrict__ deg,
                                             int* __restrict__ off,
                                             int* __restrict__ bsum) {
    __shared__ int sm[256];
    int i = blockIdx.x * 256 + threadIdx.x;
    int v = (i < N_NODES) ? deg[i] : 0;
    sm[threadIdx.x] = v;
    __syncthreads();
    for (int st = 1; st < 256; st <<= 1) {
        int t = (threadIdx.x >= (unsigned)st) ? sm[threadIdx.x - st] : 0;
        __syncthreads();
        sm[threadIdx.x] += t;
        __syncthreads();
    }
    if (i < N_NODES) off[i] = sm[threadIdx.x] - v;
    if (threadIdx.x == 255) bsum[blockIdx.x] = sm[255];
}

__global__ __launch_bounds__(256) void scan2(const int* __restrict__ bsum,
                                             int* __restrict__ boff) {
    __shared__ int sm[256];
    int b = threadIdx.x;
    int v = (b < NB_SCAN) ? bsum[b] : 0;
    sm[b] = v;
    __syncthreads();
    for (int st = 1; st < 256; st <<= 1) {
        int t = (b >= st) ? sm[b - st] : 0;
        __syncthreads();
        sm[b] += t;
        __syncthreads();
    }
    if (b < NB_SCAN) boff[b] = sm[b] - v;
    if (b == 255) boff[NB_SCAN] = sm[255];
}

__global__ __launch_bounds__(256) void scan3(int* __restrict__ off,
                                             const int* __restrict__ boff,
                                             int* __restrict__ cursor) {
    int i = blockIdx.x * 256 + threadIdx.x;
    if (i < N_NODES) {
        int v = off[i] + boff[blockIdx.x];
        off[i] = v;
        cursor[i] = v;
    }
    if (i == 0) off[N_NODES] = boff[NB_SCAN];
}

__global__ __launch_bounds__(256) void scatter_src(const int* __restrict__ ei,
                                                   int* __restrict__ cursor,
                                                   int* __restrict__ csr_src) {
    int e = blockIdx.x * 256 + threadIdx.x;
    if (e >= N_EDGES) return;
    int pos = atomicAdd(&cursor[ei[N_EDGES + e]], 1);
    csr_src[pos] = ei[e];
}

// ------------- Aggregation: wave per dst node, kv fused gather, unroll 8 ----
template <int H, bool RELU, typename OT>  // D = 64/H
__global__ __launch_bounds__(256) void agg_csr(const int* __restrict__ off,
                                               const int* __restrict__ csr_src,
                                               const bf16* __restrict__ qb,
                                               const unsigned int* __restrict__ kvu,
                                               const float* __restrict__ s,
                                               OT* __restrict__ out) {
    const int D = 64 / H;
    const float scale = (D == 16) ? 0.25f : 0.125f;
    const int lane = threadIdx.x & 63;
    const int n = (blockIdx.x * 256 + threadIdx.x) >> 6;
    if (n >= N_NODES) return;

    const float qv = __bfloat162float(qb[(size_t)n * 64 + lane]);
    float acc = 0.f, dsum = 0.f;
    int j = off[n];
    const int j1 = off[n + 1];

    for (; j + 7 < j1; j += 8) {
        unsigned int w[8];
#pragma unroll
        for (int u = 0; u < 8; ++u)
            w[u] = kvu[(size_t)csr_src[j + u] * 64 + lane];
        float p[8];
#pragma unroll
        for (int u = 0; u < 8; ++u) p[u] = qv * b2f((unsigned short)w[u]);
#pragma unroll
        for (int o = 1; o < D; o <<= 1)
#pragma unroll
            for (int u = 0; u < 8; ++u) p[u] += __shfl_xor(p[u], o, 64);
#pragma unroll
        for (int u = 0; u < 8; ++u) {
            float e = __expf(p[u] * scale);
            acc += e * b2f((unsigned short)(w[u] >> 16));
            dsum += e;
        }
    }
    for (; j < j1; ++j) {
        unsigned int w = kvu[(size_t)csr_src[j] * 64 + lane];
        float p = qv * b2f((unsigned short)w);
#pragma unroll
        for (int o = 1; o < D; o <<= 1) p += __shfl_xor(p, o, 64);
        float e = __expf(p * scale);
        acc += e * b2f((unsigned short)(w >> 16));
        dsum += e;
    }
    float a = (dsum != 0.f) ? acc / dsum : 0.f;
    float val = a + s[(size_t)n * 64 + lane];
    if (RELU) val = fmaxf(val, 0.f);
    if constexpr (__hip_internal::is_same<OT, bf16>::value)
        out[(size_t)n * 64 + lane] = __float2bfloat16(val);
    else
        out[(size_t)n * 64 + lane] = val;
}

extern "C" void kernel_launch(void* const* d_in, const int* in_sizes, int n_in,
                              void* d_out, int out_size, void* d_ws, size_t ws_size,
                              hipStream_t stream) {
    const float* x  = (const float*)d_in[0];
    const int*   ei = (const int*)d_in[1];
    const float* bq1 = (const float*)d_in[3];
    const float* bk1 = (const float*)d_in[5];
    const float* bv1 = (const float*)d_in[7];
    const float* bs1 = (const float*)d_in[9];
    const float* bq2 = (const float*)d_in[11];
    const float* bk2 = (const float*)d_in[13];
    const float* bv2 = (const float*)d_in[15];
    const float* bs2 = (const float*)d_in[17];

    WPtrs wp;
    wp.p[0] = (const float*)d_in[2];
    wp.p[1] = (const float*)d_in[4];
    wp.p[2] = (const float*)d_in[6];
    wp.p[3] = (const float*)d_in[8];
    wp.p[4] = (const float*)d_in[10];
    wp.p[5] = (const float*)d_in[12];
    wp.p[6] = (const float*)d_in[14];
    wp.p[7] = (const float*)d_in[16];

    const size_t N = N_NODES;
    bf16* xb  = (bf16*)d_ws;                 // NPAD*128
    bf16* hb  = xb + (size_t)NPAD * 128;     // NPAD*64
    bf16* qb  = hb + (size_t)NPAD * 64;      // N*64
    bf16* kvb = qb + N * 64;                 // 2*N*64 (interleaved k,v)
    bf16* wb  = kvb + 2 * N * 64;            // 49152
    float* s  = (float*)(wb + 49152);        // N*64 fp32
    int* deg  = (int*)(s + N * 64);          // N
    int* off  = deg + N_NODES;               // N+1
    int* cur  = off + N_NODES + 1;           // N
    int* bsum = cur + N_NODES;               // NB_SCAN
    int* boff = bsum + NB_SCAN;              // NB_SCAN+1
    int* csr  = boff + NB_SCAN + 1;          // E

    const int gemmGrid = NPAD / 64;          // 782
    const int edgeGrid = (N_EDGES + 255) / 256;
    const int aggGrid  = (N_NODES * 64 + 255) / 256;

    // ---------------- prep + CSR build ----------------
    hipMemsetAsync(deg, 0, N_NODES * sizeof(int), stream);
    prep<<<dim3(1024, 3), 256, 0, stream>>>(x, xb, wp, wb, ei, deg);
    scan1<<<NB_SCAN, 256, 0, stream>>>(deg, off, bsum);
    scan2<<<1, 256, 0, stream>>>(bsum, boff);
    scan3<<<NB_SCAN, 256, 0, stream>>>(off, boff, cur);
    scatter_src<<<edgeGrid, 256, 0, stream>>>(ei, cur, csr);

    // ---------------- Layer 1 ----------------
    gemm4_mfma<128><<<gemmGrid, 256, 0, stream>>>(xb, wb, bq1, bk1, bv1, bs1,
                                                  qb, kvb, s);
    agg_csr<4, true, bf16><<<aggGrid, 256, 0, stream>>>(off, csr, qb,
                                                        (const unsigned int*)kvb, s, hb);

    // ---------------- Layer 2 ----------------
    gemm4_mfma<64><<<gemmGrid, 256, 0, stream>>>(hb, wb + 32768, bq2, bk2, bv2, bs2,
                                                 qb, kvb, s);
    agg_csr<1, false, float><<<aggGrid, 256, 0, stream>>>(off, csr, qb,
                                                          (const unsigned int*)kvb, s,
                                                          (float*)d_out);
}

// Round 17
// 355.843 us; speedup vs baseline: 2.1494x; 1.0403x over previous
//
#include <hip/hip_runtime.h>
#include <hip/hip_bf16.h>

// ROUND 17. r16 = 370 us. agg_csr proven fill-BW-bound (r15==r16 at 65.7 us,
// 87.8 MB L2-miss @ ~1.56 TB/s regardless of gather count/ILP). Changes:
//  1) non-temporal loads (q, s) + nt stores (layer-2 out) in agg: stop
//     polluting per-XCD L2 with once-touched streams; L2 keeps more of the
//     12.8 MB kv gather set -> fewer misses. hb (layer-1 out) stays cached
//     (gemm2 re-reads it).
//  2) scatter_src fused into gemm1 dispatch (blocks >=782) - independent
//     work, hides ~20 us of serial scatter under the MFMA gemm.
//  3) agg unroll 16 (covers avg degree in one batch).

#define N_NODES 50000
#define N_EDGES 800000
#define NB_SCAN 196   // ceil(50000/256)
#define NPAD    50048 // 782*64
#define GEMM_BLKS 782
#define SCAT_BLKS 3125

using bf16 = __hip_bfloat16;
typedef __attribute__((ext_vector_type(8))) short bf16x8;
typedef __attribute__((ext_vector_type(4))) float f32x4;

__device__ __forceinline__ float b2f(unsigned short u) {
    unsigned int x = ((unsigned int)u) << 16;
    return __builtin_bit_cast(float, x);
}

struct WPtrs { const float* p[8]; };

// ---------------- fused prep: conv_x / conv_w / hist ----------------
__global__ __launch_bounds__(256) void prep(const float* __restrict__ x,
                                            bf16* __restrict__ xb,
                                            WPtrs wp, bf16* __restrict__ wb,
                                            const int* __restrict__ ei,
                                            int* __restrict__ deg) {
    const int gs = gridDim.x * 256;
    const int t0 = blockIdx.x * 256 + threadIdx.x;
    if (blockIdx.y == 0) {
        for (int i = t0; i < N_NODES * 128; i += gs)
            xb[i] = __float2bfloat16(x[i]);
    } else if (blockIdx.y == 1) {
        for (int i = t0; i < 49152; i += gs) {
            int y, o;
            if (i < 32768) { y = i >> 13; o = i & 8191; }
            else { y = 4 + ((i - 32768) >> 12); o = (i - 32768) & 4095; }
            wb[i] = __float2bfloat16(wp.p[y][o]);
        }
    } else {
        for (int e = t0; e < N_EDGES; e += gs)
            atomicAdd(&deg[ei[N_EDGES + e]], 1);
    }
}

// ---------------- MFMA GEMM body (64-row tile, 4 weight mats) ----------------
template <int K>
__device__ __forceinline__ void gemm_body(
    int blk, int tid,
    const bf16* __restrict__ A, const bf16* __restrict__ wb,
    const float* __restrict__ bq, const float* __restrict__ bk,
    const float* __restrict__ bv, const float* __restrict__ bs,
    bf16* __restrict__ qb, bf16* __restrict__ kvb, float* __restrict__ s) {
    const int wave = tid >> 6;
    const int lane = tid & 63;
    const int row0 = blk * 64;
    const int m  = lane & 15;
    const int kg = lane >> 4;
    const bf16* W = wb + (size_t)wave * 64 * K;

    f32x4 acc[4][4];
#pragma unroll
    for (int i = 0; i < 4; ++i)
#pragma unroll
        for (int j = 0; j < 4; ++j) acc[i][j] = (f32x4){0.f, 0.f, 0.f, 0.f};

#pragma unroll
    for (int k0 = 0; k0 < K; k0 += 32) {
        bf16x8 a[4], b[4];
#pragma unroll
        for (int i = 0; i < 4; ++i)
            a[i] = *(const bf16x8*)(A + (size_t)(row0 + i * 16 + m) * K + k0 + kg * 8);
#pragma unroll
        for (int j = 0; j < 4; ++j)
            b[j] = *(const bf16x8*)(W + (size_t)(j * 16 + m) * K + k0 + kg * 8);
#pragma unroll
        for (int i = 0; i < 4; ++i)
#pragma unroll
            for (int j = 0; j < 4; ++j)
                acc[i][j] = __builtin_amdgcn_mfma_f32_16x16x32_bf16(a[i], b[j], acc[i][j], 0, 0, 0);
    }

    const int crow = (lane >> 4) * 4;
    const int ccol = lane & 15;
    const float* B = (wave == 0) ? bq : (wave == 1) ? bk : (wave == 2) ? bv : bs;
    float bias[4];
#pragma unroll
    for (int j = 0; j < 4; ++j) bias[j] = B[j * 16 + ccol];

#pragma unroll
    for (int i = 0; i < 4; ++i)
#pragma unroll
        for (int r = 0; r < 4; ++r) {
            int gr = row0 + i * 16 + crow + r;
            if (gr >= N_NODES) continue;
#pragma unroll
            for (int j = 0; j < 4; ++j) {
                float val = acc[i][j][r] + bias[j];
                size_t idx = (size_t)gr * 64 + j * 16 + ccol;
                if (wave == 0) qb[idx] = __float2bfloat16(val);
                else if (wave == 1) kvb[idx * 2] = __float2bfloat16(val);
                else if (wave == 2) kvb[idx * 2 + 1] = __float2bfloat16(val);
                else s[idx] = val;
            }
        }
}

// layer-1 GEMM + scatter fused (independent work in one dispatch)
__global__ __launch_bounds__(256) void gemm1_scatter(
    const bf16* __restrict__ A, const bf16* __restrict__ wb,
    const float* __restrict__ bq, const float* __restrict__ bk,
    const float* __restrict__ bv, const float* __restrict__ bs,
    bf16* __restrict__ qb, bf16* __restrict__ kvb, float* __restrict__ s,
    const int* __restrict__ ei, int* __restrict__ cursor,
    int* __restrict__ csr_src) {
    if (blockIdx.x < GEMM_BLKS) {
        gemm_body<128>(blockIdx.x, threadIdx.x, A, wb, bq, bk, bv, bs, qb, kvb, s);
    } else {
        int e = (blockIdx.x - GEMM_BLKS) * 256 + threadIdx.x;
        if (e < N_EDGES) {
            int pos = atomicAdd(&cursor[ei[N_EDGES + e]], 1);
            csr_src[pos] = ei[e];
        }
    }
}

__global__ __launch_bounds__(256) void gemm2(
    const bf16* __restrict__ A, const bf16* __restrict__ wb,
    const float* __restrict__ bq, const float* __restrict__ bk,
    const float* __restrict__ bv, const float* __restrict__ bs,
    bf16* __restrict__ qb, bf16* __restrict__ kvb, float* __restrict__ s) {
    gemm_body<64>(blockIdx.x, threadIdx.x, A, wb, bq, bk, bv, bs, qb, kvb, s);
}

// ---------------- CSR scan ----------------
__global__ __launch_bounds__(256) void scan1(const int* __restrict__ deg,
                                             int* __restrict__ off,
                                             int* __restrict__ bsum) {
    __shared__ int sm[256];
    int i = blockIdx.x * 256 + threadIdx.x;
    int v = (i < N_NODES) ? deg[i] : 0;
    sm[threadIdx.x] = v;
    __syncthreads();
    for (int st = 1; st < 256; st <<= 1) {
        int t = (threadIdx.x >= (unsigned)st) ? sm[threadIdx.x - st] : 0;
        __syncthreads();
        sm[threadIdx.x] += t;
        __syncthreads();
    }
    if (i < N_NODES) off[i] = sm[threadIdx.x] - v;
    if (threadIdx.x == 255) bsum[blockIdx.x] = sm[255];
}

__global__ __launch_bounds__(256) void scan2(const int* __restrict__ bsum,
                                             int* __restrict__ boff) {
    __shared__ int sm[256];
    int b = threadIdx.x;
    int v = (b < NB_SCAN) ? bsum[b] : 0;
    sm[b] = v;
    __syncthreads();
    for (int st = 1; st < 256; st <<= 1) {
        int t = (b >= st) ? sm[b - st] : 0;
        __syncthreads();
        sm[b] += t;
        __syncthreads();
    }
    if (b < NB_SCAN) boff[b] = sm[b] - v;
    if (b == 255) boff[NB_SCAN] = sm[255];
}

__global__ __launch_bounds__(256) void scan3(int* __restrict__ off,
                                             const int* __restrict__ boff,
                                             int* __restrict__ cursor) {
    int i = blockIdx.x * 256 + threadIdx.x;
    if (i < N_NODES) {
        int v = off[i] + boff[blockIdx.x];
        off[i] = v;
        cursor[i] = v;
    }
    if (i == 0) off[N_NODES] = boff[NB_SCAN];
}

// ------------- Aggregation: wave/node, nt streaming, unroll 16 -------------
template <int H, bool RELU, typename OT>  // D = 64/H
__global__ __launch_bounds__(256) void agg_csr(const int* __restrict__ off,
                                               const int* __restrict__ csr_src,
                                               const bf16* __restrict__ qb,
                                               const unsigned int* __restrict__ kvu,
                                               const float* __restrict__ s,
                                               OT* __restrict__ out) {
    const int D = 64 / H;
    const float scale = (D == 16) ? 0.25f : 0.125f;
    const int lane = threadIdx.x & 63;
    const int n = (blockIdx.x * 256 + threadIdx.x) >> 6;
    if (n >= N_NODES) return;

    // q read once -> non-temporal (don't evict kv rows from L2)
    const float qv = b2f(__builtin_nontemporal_load(
        (const unsigned short*)qb + (size_t)n * 64 + lane));
    float acc = 0.f, dsum = 0.f;
    int j = off[n];
    const int j1 = off[n + 1];

    for (; j + 15 < j1; j += 16) {
        unsigned int w[16];
#pragma unroll
        for (int u = 0; u < 16; ++u)
            w[u] = kvu[(size_t)csr_src[j + u] * 64 + lane];
        float p[16];
#pragma unroll
        for (int u = 0; u < 16; ++u) p[u] = qv * b2f((unsigned short)w[u]);
#pragma unroll
        for (int o = 1; o < D; o <<= 1)
#pragma unroll
            for (int u = 0; u < 16; ++u) p[u] += __shfl_xor(p[u], o, 64);
#pragma unroll
        for (int u = 0; u < 16; ++u) {
            float e = __expf(p[u] * scale);
            acc += e * b2f((unsigned short)(w[u] >> 16));
            dsum += e;
        }
    }
    for (; j + 3 < j1; j += 4) {
        unsigned int w[4];
#pragma unroll
        for (int u = 0; u < 4; ++u)
            w[u] = kvu[(size_t)csr_src[j + u] * 64 + lane];
        float p[4];
#pragma unroll
        for (int u = 0; u < 4; ++u) p[u] = qv * b2f((unsigned short)w[u]);
#pragma unroll
        for (int o = 1; o < D; o <<= 1)
#pragma unroll
            for (int u = 0; u < 4; ++u) p[u] += __shfl_xor(p[u], o, 64);
#pragma unroll
        for (int u = 0; u < 4; ++u) {
            float e = __expf(p[u] * scale);
            acc += e * b2f((unsigned short)(w[u] >> 16));
            dsum += e;
        }
    }
    for (; j < j1; ++j) {
        unsigned int w = kvu[(size_t)csr_src[j] * 64 + lane];
        float p = qv * b2f((unsigned short)w);
#pragma unroll
        for (int o = 1; o < D; o <<= 1) p += __shfl_xor(p, o, 64);
        float e = __expf(p * scale);
        acc += e * b2f((unsigned short)(w >> 16));
        dsum += e;
    }
    float a = (dsum != 0.f) ? acc / dsum : 0.f;
    float sk = __builtin_nontemporal_load(s + (size_t)n * 64 + lane);
    float val = a + sk;
    if (RELU) val = fmaxf(val, 0.f);
    if constexpr (__hip_internal::is_same<OT, bf16>::value)
        out[(size_t)n * 64 + lane] = __float2bfloat16(val);  // hb: re-read by gemm2, keep cached
    else
        __builtin_nontemporal_store(val, out + (size_t)n * 64 + lane);  // d_out: nt
}

extern "C" void kernel_launch(void* const* d_in, const int* in_sizes, int n_in,
                              void* d_out, int out_size, void* d_ws, size_t ws_size,
                              hipStream_t stream) {
    const float* x  = (const float*)d_in[0];
    const int*   ei = (const int*)d_in[1];
    const float* bq1 = (const float*)d_in[3];
    const float* bk1 = (const float*)d_in[5];
    const float* bv1 = (const float*)d_in[7];
    const float* bs1 = (const float*)d_in[9];
    const float* bq2 = (const float*)d_in[11];
    const float* bk2 = (const float*)d_in[13];
    const float* bv2 = (const float*)d_in[15];
    const float* bs2 = (const float*)d_in[17];

    WPtrs wp;
    wp.p[0] = (const float*)d_in[2];
    wp.p[1] = (const float*)d_in[4];
    wp.p[2] = (const float*)d_in[6];
    wp.p[3] = (const float*)d_in[8];
    wp.p[4] = (const float*)d_in[10];
    wp.p[5] = (const float*)d_in[12];
    wp.p[6] = (const float*)d_in[14];
    wp.p[7] = (const float*)d_in[16];

    const size_t N = N_NODES;
    bf16* xb  = (bf16*)d_ws;                 // NPAD*128
    bf16* hb  = xb + (size_t)NPAD * 128;     // NPAD*64
    bf16* qb  = hb + (size_t)NPAD * 64;      // N*64
    bf16* kvb = qb + N * 64;                 // 2*N*64 interleaved
    bf16* wb  = kvb + 2 * N * 64;            // 49152
    float* s  = (float*)(wb + 49152);        // N*64
    int* deg  = (int*)(s + N * 64);          // N
    int* off  = deg + N_NODES;               // N+1
    int* cur  = off + N_NODES + 1;           // N
    int* bsum = cur + N_NODES;               // NB_SCAN
    int* boff = bsum + NB_SCAN;              // NB_SCAN+1
    int* csr  = boff + NB_SCAN + 1;          // E

    const int aggGrid = (N_NODES * 64 + 255) / 256;

    // ---------------- prep + CSR ----------------
    hipMemsetAsync(deg, 0, N_NODES * sizeof(int), stream);
    prep<<<dim3(1024, 3), 256, 0, stream>>>(x, xb, wp, wb, ei, deg);
    scan1<<<NB_SCAN, 256, 0, stream>>>(deg, off, bsum);
    scan2<<<1, 256, 0, stream>>>(bsum, boff);
    scan3<<<NB_SCAN, 256, 0, stream>>>(off, boff, cur);

    // ---------------- Layer 1 (gemm + scatter fused) ----------------
    gemm1_scatter<<<GEMM_BLKS + SCAT_BLKS, 256, 0, stream>>>(
        xb, wb, bq1, bk1, bv1, bs1, qb, kvb, s, ei, cur, csr);
    agg_csr<4, true, bf16><<<aggGrid, 256, 0, stream>>>(off, csr, qb,
                                                        (const unsigned int*)kvb, s, hb);

    // ---------------- Layer 2 ----------------
    gemm2<<<GEMM_BLKS, 256, 0, stream>>>(hb, wb + 32768, bq2, bk2, bv2, bs2,
                                         qb, kvb, s);
    agg_csr<1, false, float><<<aggGrid, 256, 0, stream>>>(off, csr, qb,
                                                          (const unsigned int*)kvb, s,
                                                          (float*)d_out);
}